// Round 11
// baseline (517.585 us; speedup 1.0000x reference)
//
#include <hip/hip_runtime.h>
#include <hip/hip_bf16.h>

#define NPTS 16384
#define DIM  2048
#define NGRP 4096
#define BKF  128
#define NTF  (DIM / BKF)   // 16 K-tiles

typedef __bf16 bf16x8 __attribute__((ext_vector_type(8)));
typedef unsigned short u16x8 __attribute__((ext_vector_type(8)));
typedef float f32x4 __attribute__((ext_vector_type(4)));
typedef int i32x4 __attribute__((ext_vector_type(4)));
typedef int i32x8 __attribute__((ext_vector_type(8)));

__device__ __forceinline__ unsigned short f2bf(float f) {
  union { float f; unsigned u; } v; v.f = f;
  unsigned u = v.u;
  return (unsigned short)((u + 0x7FFFu + ((u >> 16) & 1u)) >> 16);  // RTNE
}
__device__ __forceinline__ float bflo(unsigned u) { return __uint_as_float(u << 16); }
__device__ __forceinline__ float bfhi(unsigned u) { return __uint_as_float(u & 0xffff0000u); }

// 4 floats -> 4 OCP e4m3 bytes (RNE, saturating) in one u32.  [R6/R8-verified]
__device__ __forceinline__ unsigned cvtpk4(float a, float b, float c, float d) {
  int w = __builtin_amdgcn_cvt_pk_fp8_f32(a, b, 0, false);   // bytes 0,1
  w = __builtin_amdgcn_cvt_pk_fp8_f32(c, d, w, true);        // bytes 2,3
  return (unsigned)w;
}

// Async global->LDS, 16B per lane. LDS dest is wave-uniform base + lane*16.
__device__ __forceinline__ void gload16(const void* g, void* lds) {
  __builtin_amdgcn_global_load_lds(
      (const __attribute__((address_space(1))) unsigned*)g,
      (__attribute__((address_space(3))) unsigned*)lds, 16, 0, 0);
}

// Per-wave deterministic dtype sniff: all waves inspect X[0..63] -> identical verdict.
__device__ __forceinline__ bool sniff_bf16(const void* X) {
  const int lane = threadIdx.x & 63;
  unsigned hb = (((const unsigned short*)X)[lane] >> 8) & 0x7Fu;
  unsigned long long m = __ballot(hb >= 0x3Bu && hb <= 0x41u);
  return __popcll(m) >= 48;
}

// ---- fused prep: self-sniff + exact-fp32 row norms + fp8 e4m3 operand copy.
// (R8-verified) ----
__global__ __launch_bounds__(256) void prep_all_kernel(
    const void* __restrict__ Xin, const void* __restrict__ Ein,
    unsigned char* __restrict__ Xf8, unsigned char* __restrict__ Ef8,
    float* __restrict__ x2, float* __restrict__ e2) {
  const int lane  = threadIdx.x & 63;
  const int wavei = threadIdx.x >> 6;
  const bool isbf = sniff_bf16(Xin);

  const int grow = blockIdx.x * 4 + wavei;
  const void* in; unsigned char* q; float* nrm; int row;
  if (grow < NPTS) { in = Xin; q = Xf8; nrm = x2; row = grow; }
  else             { in = Ein; q = Ef8; nrm = e2; row = grow - NPTS; }

  unsigned char* qq = q + (size_t)row * DIM;
  float s = 0.f;
#pragma unroll
  for (int it = 0; it < 4; ++it) {
    float v0, v1, v2, v3, v4, v5, v6, v7;
    if (isbf) {
      const unsigned short* p = (const unsigned short*)in + (size_t)row * DIM;
      uint4 r = *(const uint4*)(p + it * 512 + lane * 8);
      v0 = bflo(r.x); v1 = bfhi(r.x); v2 = bflo(r.y); v3 = bfhi(r.y);
      v4 = bflo(r.z); v5 = bfhi(r.z); v6 = bflo(r.w); v7 = bfhi(r.w);
    } else {
      const float* p = (const float*)in + (size_t)row * DIM;
      float4 a = *(const float4*)(p + it * 512 + lane * 8);
      float4 b = *(const float4*)(p + it * 512 + lane * 8 + 4);
      v0 = a.x; v1 = a.y; v2 = a.z; v3 = a.w;
      v4 = b.x; v5 = b.y; v6 = b.z; v7 = b.w;
    }
    s += v0 * v0 + v1 * v1 + v2 * v2 + v3 * v3;
    s += v4 * v4 + v5 * v5 + v6 * v6 + v7 * v7;
    uint2 w;
    w.x = cvtpk4(v0, v1, v2, v3);
    w.y = cvtpk4(v4, v5, v6, v7);
    *(uint2*)(qq + it * 512 + lane * 8) = w;
  }
#pragma unroll
  for (int off = 32; off > 0; off >>= 1) s += __shfl_down(s, off, 64);
  if (lane == 0) nrm[row] = s;
}

// ---- 256x256 8-wave MX-fp8 GEMM (R8 core) with EARLY-DRAIN BARRIER:
//      per tile: vmcnt(8)+barrier -> ALL 12 frag reads to regs -> lgkmcnt(0)
//      -> barrier -> STAGE(t+2) -> 32 register-fed MFMAs.
//      Moves stage issue one full MFMA phase earlier: the staging stream no
//      longer waits for the slowest wave's compute. Numerics bit-identical
//      to R8 (same instrs, same order). Risk: 3 live frag sets (~245 VGPR). ----
__global__ __launch_bounds__(512, 2) void gemm_mx_kernel(
    const void* __restrict__ Xin,            // output-dtype sniff only
    const unsigned char* __restrict__ X8, const unsigned char* __restrict__ E8,
    const float* __restrict__ x2, const float* __restrict__ e2,
    void* __restrict__ outv) {
  // [buf][ A: 256x128 fp8 (32KB) | B: 256x128 fp8 (32KB) ] = 2 x 64KB = 128KB
  __shared__ __align__(16) unsigned char sbuf[2][65536];

  const int tid  = threadIdx.x;
  const int lane = tid & 63;
  const int wave = tid >> 6;   // 0..7
  const int wm   = wave >> 2;  // 0..1  (M half: 128 rows)
  const int wn   = wave & 3;   // 0..3  (N quarter: 64 cols)
  const int quad = lane >> 4;
  const int l16  = lane & 15;

  const bool isbf = sniff_bf16(Xin);

  const int rowBase = blockIdx.y * 256;
  const int colBase = blockIdx.x * 256;

  // Staging: 8 gloads/thread/tile. gload g covers rows [g*64, g*64+64) (8KB).
  // Thread t: dest row = g*64 + (t>>3), dest col-byte = (t&7)*16 (linear).
  // Inverse-swizzled SOURCE col: ((t&7) ^ ((t>>3)&7)) * 16 bytes.
  const int srow  = tid >> 3;                         // 0..63
  const int scol  = ((tid & 7) ^ (srow & 7)) * 16;    // source col (bytes)
  size_t gAo[4], gBo[4];
#pragma unroll
  for (int g = 0; g < 4; ++g) {
    gAo[g] = (size_t)(rowBase + g * 64 + srow) * DIM + scol;
    gBo[g] = (size_t)(colBase + g * 64 + srow) * DIM + scol;
  }

  // Fragment reads (16x16x128): lane -> row = l16 (+16*frag), k = quad*32+[0,32)
  // = two b128 at swizzled cb = ((quad*2 + h) ^ (l16&7)) * 16, h = 0,1.
  const int cb0 = ((quad * 2) ^ (l16 & 7)) * 16;

  f32x4 acc[8][4];
#pragma unroll
  for (int mt = 0; mt < 8; ++mt)
#pragma unroll
    for (int nt = 0; nt < 4; ++nt) acc[mt][nt] = f32x4{0.f, 0.f, 0.f, 0.f};

  i32x8 a8[4], b8[4], c8[4];   // A-low, B, A-high fragment sets (all live)

#define STAGE(t_) do { unsigned char* sb_ = sbuf[(t_) & 1];                     \
    const size_t kk_ = (size_t)(t_) * BKF;                                      \
    _Pragma("unroll") for (int g = 0; g < 4; ++g)                               \
      gload16(X8 + gAo[g] + kk_, sb_ + g * 8192 + wave * 1024);                 \
    _Pragma("unroll") for (int g = 0; g < 4; ++g)                               \
      gload16(E8 + gBo[g] + kk_, sb_ + 32768 + g * 8192 + wave * 1024);         \
  } while (0)

  // Load one i32x8 fragment (32 fp8 = k quad*32..+32) from swizzled LDS row.
#define LDFRAG(dst_, base_, rowi_) do {                                         \
    const unsigned char* p_ = (base_) + (rowi_) * 128;                          \
    i32x4 lo_ = *(const i32x4*)(const void*)(p_ + cb0);                         \
    i32x4 hi_ = *(const i32x4*)(const void*)(p_ + (cb0 ^ 16));                  \
    dst_[0] = lo_[0]; dst_[1] = lo_[1]; dst_[2] = lo_[2]; dst_[3] = lo_[3];     \
    dst_[4] = hi_[0]; dst_[5] = hi_[1]; dst_[6] = hi_[2]; dst_[7] = hi_[3];     \
  } while (0)

#define MFMA16(AARR_, MOFF_) do {                                               \
    __builtin_amdgcn_s_setprio(1);                                              \
    _Pragma("unroll") for (int m = 0; m < 4; ++m)                               \
      _Pragma("unroll") for (int n = 0; n < 4; ++n)                             \
        acc[(MOFF_) + m][n] = __builtin_amdgcn_mfma_scale_f32_16x16x128_f8f6f4( \
            AARR_[m], b8[n], acc[(MOFF_) + m][n], 0, 0,                         \
            0, 0x7F7F7F7F, 0, 0x7F7F7F7F);   /* E8M0 0x7F = scale 1.0 */        \
    __builtin_amdgcn_s_setprio(0);                                              \
  } while (0)

  // Race audit: entry {vmcnt(8); barrier} -> tile t resident (oldest 8 loads
  // drained for every wave). All 12 frag reads issued, then per-wave
  // lgkmcnt(0) -> every wave's reads of buf[t&1] COMPLETE before its barrier
  // arrival -> after the mid barrier, STAGE(t+2) may overwrite buf[t&1] while
  // MFMAs run on registers only. vmcnt count at entry t+1: outstanding =
  // t+1's 8 + t+2's 8 -> vmcnt(8) drains exactly t+1's. Tail: 8 -> 0 as R8.
#define BODY(t_, DOSTAGE_, VMS_) do {                                           \
    asm volatile("s_waitcnt vmcnt(" VMS_ ")" ::: "memory");                     \
    __builtin_amdgcn_s_barrier();                                               \
    __builtin_amdgcn_sched_barrier(0);                                          \
    const unsigned char* sa_ = sbuf[(t_) & 1];                                  \
    const unsigned char* sb2_ = sa_ + 32768;                                    \
    _Pragma("unroll") for (int m = 0; m < 4; ++m)                               \
      LDFRAG(a8[m], sa_, (wm * 128 + m * 16 + l16));                            \
    _Pragma("unroll") for (int n = 0; n < 4; ++n)                               \
      LDFRAG(b8[n], sb2_, (wn * 64 + n * 16 + l16));                            \
    _Pragma("unroll") for (int m = 0; m < 4; ++m)                               \
      LDFRAG(c8[m], sa_, (wm * 128 + (m + 4) * 16 + l16));                      \
    asm volatile("s_waitcnt lgkmcnt(0)" ::: "memory");                          \
    __builtin_amdgcn_sched_barrier(0);       /* rule #18 */                     \
    __builtin_amdgcn_s_barrier();            /* all waves' reads done */        \
    __builtin_amdgcn_sched_barrier(0);                                          \
    if (DOSTAGE_) STAGE((t_) + 2);           /* overlaps MFMA phase below */    \
    MFMA16(a8, 0);                                                              \
    MFMA16(c8, 4);                                                              \
    asm volatile("" ::: "memory");                                              \
  } while (0)

  // Prologue: tiles 0,1 staged (16 loads/thread).
  STAGE(0); STAGE(1);

#pragma unroll 1
  for (int t = 0; t < NTF - 2; ++t) {
    BODY(t, true, "8");
  }
  BODY(NTF - 2, false, "8");
  BODY(NTF - 1, false, "0");
#undef BODY
#undef MFMA16
#undef LDFRAG
#undef STAGE

  // Epilogue. 16x16 C/D layout: col = lane&15, row = quad*4 + reg
  // (shape-determined, FMT-independent — R8-verified).
  float ec[4];
#pragma unroll
  for (int nt = 0; nt < 4; ++nt) ec[nt] = e2[colBase + wn * 64 + nt * 16 + l16];

  if (isbf) {
    unsigned short* out = (unsigned short*)outv;
#pragma unroll
    for (int mt = 0; mt < 8; ++mt)
#pragma unroll
      for (int r2 = 0; r2 < 4; ++r2) {
        const int row = rowBase + wm * 128 + mt * 16 + quad * 4 + r2;
        const float xr = x2[row];
#pragma unroll
        for (int nt = 0; nt < 4; ++nt) {
          const int col = colBase + wn * 64 + nt * 16 + l16;
          float sq = xr + ec[nt] - 2.0f * acc[mt][nt][r2];
          sq = sq > 0.f ? sq : 0.f;
          out[(size_t)row * NGRP + col] = f2bf(-__builtin_sqrtf(sq));
        }
      }
  } else {
    float* out = (float*)outv;
#pragma unroll
    for (int mt = 0; mt < 8; ++mt)
#pragma unroll
      for (int r2 = 0; r2 < 4; ++r2) {
        const int row = rowBase + wm * 128 + mt * 16 + quad * 4 + r2;
        const float xr = x2[row];
#pragma unroll
        for (int nt = 0; nt < 4; ++nt) {
          const int col = colBase + wn * 64 + nt * 16 + l16;
          float sq = xr + ec[nt] - 2.0f * acc[mt][nt][r2];
          sq = sq > 0.f ? sq : 0.f;
          out[(size_t)row * NGRP + col] = -__builtin_sqrtf(sq);
        }
      }
  }
}

// ---------------- fallback path (workspace too small): round-0 kernels ----------------

__global__ void sniff_kernel(const unsigned short* __restrict__ X, int* __restrict__ flag) {
  if (threadIdx.x == 0 && blockIdx.x == 0) {
    int c = 0;
    for (int i = 0; i < 64; ++i) {
      unsigned b = (X[i] >> 8) & 0x7F;
      c += (b >= 0x3B && b <= 0x41) ? 1 : 0;
    }
    *flag = (c >= 48) ? 1 : 0;
  }
}

__global__ __launch_bounds__(256) void rownorm_kernel(const void* __restrict__ in,
                                                      float* __restrict__ out,
                                                      const int* __restrict__ flag) {
  const int wave = threadIdx.x >> 6;
  const int lane = threadIdx.x & 63;
  const int row  = blockIdx.x * 4 + wave;
  float s = 0.f;
  if (*flag) {
    const unsigned short* p = (const unsigned short*)in + (size_t)row * DIM;
#pragma unroll
    for (int it = 0; it < 4; ++it) {
      uint4 v = *(const uint4*)(p + it * 512 + lane * 8);
      float f;
      f = bflo(v.x); s += f * f;  f = bfhi(v.x); s += f * f;
      f = bflo(v.y); s += f * f;  f = bfhi(v.y); s += f * f;
      f = bflo(v.z); s += f * f;  f = bfhi(v.z); s += f * f;
      f = bflo(v.w); s += f * f;  f = bfhi(v.w); s += f * f;
    }
  } else {
    const float* p = (const float*)in + (size_t)row * DIM;
#pragma unroll
    for (int it = 0; it < 4; ++it) {
      float4 a = *(const float4*)(p + it * 512 + lane * 8);
      float4 b = *(const float4*)(p + it * 512 + lane * 8 + 4);
      s += a.x * a.x + a.y * a.y + a.z * a.z + a.w * a.w;
      s += b.x * b.x + b.y * b.y + b.z * b.z + b.w * b.w;
    }
  }
#pragma unroll
  for (int off = 32; off > 0; off >>= 1) s += __shfl_down(s, off, 64);
  if (lane == 0) out[row] = s;
}

__device__ __forceinline__ u16x8 cvt8(const float* p) {
  float4 a = *(const float4*)p;
  float4 b = *(const float4*)(p + 4);
  u16x8 r;
  r[0] = f2bf(a.x); r[1] = f2bf(a.y); r[2] = f2bf(a.z); r[3] = f2bf(a.w);
  r[4] = f2bf(b.x); r[5] = f2bf(b.y); r[6] = f2bf(b.z); r[7] = f2bf(b.w);
  return r;
}

__global__ __launch_bounds__(256) void gemm_dist_kernel(
    const void* __restrict__ Xv, const void* __restrict__ Ev,
    const float* __restrict__ x2, const float* __restrict__ e2,
    void* __restrict__ outv, const int* __restrict__ flag) {
  __shared__ __align__(16) unsigned short sA[128 * 32];
  __shared__ __align__(16) unsigned short sB[128 * 32];

  const bool isbf = (*flag != 0);
  const int tid  = threadIdx.x;
  const int lane = tid & 63;
  const int wave = tid >> 6;
  const int wm   = wave >> 1;
  const int wn   = wave & 1;
  const int quad = lane >> 4;
  const int l16  = lane & 15;

  const int rowBase = blockIdx.y * 128;
  const int colBase = blockIdx.x * 128;

  const int flat0 = tid * 8;
  const int flat1 = (tid + 256) * 8;
  const int r0 = flat0 >> 5, c0 = flat0 & 31;
  const int r1 = flat1 >> 5, c1 = flat1 & 31;

  const size_t iA0 = (size_t)(rowBase + r0) * DIM + c0;
  const size_t iA1 = (size_t)(rowBase + r1) * DIM + c1;
  const size_t iB0 = (size_t)(colBase + r0) * DIM + c0;
  const size_t iB1 = (size_t)(colBase + r1) * DIM + c1;

  f32x4 zero = {0.f, 0.f, 0.f, 0.f};
  f32x4 acc[4][4];
#pragma unroll
  for (int mt = 0; mt < 4; ++mt)
#pragma unroll
    for (int nt = 0; nt < 4; ++nt) acc[mt][nt] = zero;

  for (int k0 = 0; k0 < DIM; k0 += 32) {
    if (isbf) {
      const unsigned short* X = (const unsigned short*)Xv;
      const unsigned short* E = (const unsigned short*)Ev;
      *(uint4*)(sA + flat0) = *(const uint4*)(X + iA0 + k0);
      *(uint4*)(sA + flat1) = *(const uint4*)(X + iA1 + k0);
      *(uint4*)(sB + flat0) = *(const uint4*)(E + iB0 + k0);
      *(uint4*)(sB + flat1) = *(const uint4*)(E + iB1 + k0);
    } else {
      const float* X = (const float*)Xv;
      const float* E = (const float*)Ev;
      *(u16x8*)(sA + flat0) = cvt8(X + iA0 + k0);
      *(u16x8*)(sA + flat1) = cvt8(X + iA1 + k0);
      *(u16x8*)(sB + flat0) = cvt8(E + iB0 + k0);
      *(u16x8*)(sB + flat1) = cvt8(E + iB1 + k0);
    }
    __syncthreads();

    bf16x8 a[4], b[4];
#pragma unroll
    for (int mt = 0; mt < 4; ++mt)
      a[mt] = *(const bf16x8*)(const void*)(sA + (wm * 64 + mt * 16 + l16) * 32 + quad * 8);
#pragma unroll
    for (int nt = 0; nt < 4; ++nt)
      b[nt] = *(const bf16x8*)(const void*)(sB + (wn * 64 + nt * 16 + l16) * 32 + quad * 8);
#pragma unroll
    for (int mt = 0; mt < 4; ++mt)
#pragma unroll
      for (int nt = 0; nt < 4; ++nt)
        acc[mt][nt] = __builtin_amdgcn_mfma_f32_16x16x32_bf16(a[mt], b[nt], acc[mt][nt], 0, 0, 0);
    __syncthreads();
  }

  float ec[4];
#pragma unroll
  for (int nt = 0; nt < 4; ++nt) ec[nt] = e2[colBase + wn * 64 + nt * 16 + l16];

  if (isbf) {
    unsigned short* out = (unsigned short*)outv;
#pragma unroll
    for (int mt = 0; mt < 4; ++mt)
#pragma unroll
      for (int r = 0; r < 4; ++r) {
        const int row = rowBase + wm * 64 + mt * 16 + quad * 4 + r;
        const float xr = x2[row];
#pragma unroll
        for (int nt = 0; nt < 4; ++nt) {
          const int col = colBase + wn * 64 + nt * 16 + l16;
          float sq = xr + ec[nt] - 2.0f * acc[mt][nt][r];
          sq = sq > 0.f ? sq : 0.f;
          out[(size_t)row * NGRP + col] = f2bf(-__builtin_sqrtf(sq));
        }
      }
  } else {
    float* out = (float*)outv;
#pragma unroll
    for (int mt = 0; mt < 4; ++mt)
#pragma unroll
      for (int r = 0; r < 4; ++r) {
        const int row = rowBase + wm * 64 + mt * 16 + quad * 4 + r;
        const float xr = x2[row];
#pragma unroll
        for (int nt = 0; nt < 4; ++nt) {
          const int col = colBase + wn * 64 + nt * 16 + l16;
          float sq = xr + ec[nt] - 2.0f * acc[mt][nt][r];
          sq = sq > 0.f ? sq : 0.f;
          out[(size_t)row * NGRP + col] = -__builtin_sqrtf(sq);
        }
      }
  }
}

extern "C" void kernel_launch(void* const* d_in, const int* in_sizes, int n_in,
                              void* d_out, int out_size, void* d_ws, size_t ws_size,
                              hipStream_t stream) {
  const size_t xf8 = (size_t)NPTS * DIM;
  const size_t ef8 = (size_t)NGRP * DIM;
  const size_t need = xf8 + ef8 + (NPTS + NGRP) * sizeof(float) + 64;

  if (ws_size >= need) {
    // Fast path: fused prep (exact norms + fp8 copy) + MX-fp8 K=128 GEMM
    // with early-drain barrier (stage overlaps MFMA phase).
    unsigned char* Xf8 = (unsigned char*)d_ws;
    unsigned char* Ef8 = Xf8 + xf8;
    float* x2 = (float*)(Ef8 + ef8);
    float* e2 = x2 + NPTS;

    prep_all_kernel<<<(NPTS + NGRP) / 4, 256, 0, stream>>>(d_in[0], d_in[1],
                                                           Xf8, Ef8, x2, e2);
    dim3 grid(NGRP / 256, NPTS / 256);
    gemm_mx_kernel<<<grid, 512, 0, stream>>>(d_in[0], Xf8, Ef8, x2, e2, d_out);
  } else {
    // Fallback: round-0 verified bf16 path.
    float* x2 = (float*)d_ws;
    float* e2 = x2 + NPTS;
    int* flag = (int*)(e2 + NGRP);

    sniff_kernel<<<1, 64, 0, stream>>>((const unsigned short*)d_in[0], flag);
    rownorm_kernel<<<NPTS / 4, 256, 0, stream>>>(d_in[0], x2, flag);
    rownorm_kernel<<<NGRP / 4, 256, 0, stream>>>(d_in[1], e2, flag);
    dim3 grid(NGRP / 128, NPTS / 128);
    gemm_dist_kernel<<<grid, 256, 0, stream>>>(d_in[0], d_in[1], x2, e2, d_out, flag);
  }
}

// Round 12
// 507.266 us; speedup vs baseline: 1.0203x; 1.0203x over previous
//
#include <hip/hip_runtime.h>
#include <hip/hip_bf16.h>

#define NPTS 16384
#define DIM  2048
#define NGRP 4096
#define BKF  128
#define NTF  (DIM / BKF)   // 16 K-tiles

typedef __bf16 bf16x8 __attribute__((ext_vector_type(8)));
typedef unsigned short u16x8 __attribute__((ext_vector_type(8)));
typedef float f32x4 __attribute__((ext_vector_type(4)));
typedef int i32x4 __attribute__((ext_vector_type(4)));
typedef int i32x8 __attribute__((ext_vector_type(8)));

__device__ __forceinline__ unsigned short f2bf(float f) {
  union { float f; unsigned u; } v; v.f = f;
  unsigned u = v.u;
  return (unsigned short)((u + 0x7FFFu + ((u >> 16) & 1u)) >> 16);  // RTNE
}
__device__ __forceinline__ float bflo(unsigned u) { return __uint_as_float(u << 16); }
__device__ __forceinline__ float bfhi(unsigned u) { return __uint_as_float(u & 0xffff0000u); }

// 4 floats -> 4 OCP e4m3 bytes (RNE, saturating) in one u32.  [R6/R8-verified]
__device__ __forceinline__ unsigned cvtpk4(float a, float b, float c, float d) {
  int w = __builtin_amdgcn_cvt_pk_fp8_f32(a, b, 0, false);   // bytes 0,1
  w = __builtin_amdgcn_cvt_pk_fp8_f32(c, d, w, true);        // bytes 2,3
  return (unsigned)w;
}

// Async global->LDS, 16B per lane. LDS dest is wave-uniform base + lane*16.
__device__ __forceinline__ void gload16(const void* g, void* lds) {
  __builtin_amdgcn_global_load_lds(
      (const __attribute__((address_space(1))) unsigned*)g,
      (__attribute__((address_space(3))) unsigned*)lds, 16, 0, 0);
}

// Per-wave deterministic dtype sniff: all waves inspect X[0..63] -> identical verdict.
__device__ __forceinline__ bool sniff_bf16(const void* X) {
  const int lane = threadIdx.x & 63;
  unsigned hb = (((const unsigned short*)X)[lane] >> 8) & 0x7Fu;
  unsigned long long m = __ballot(hb >= 0x3Bu && hb <= 0x41u);
  return __popcll(m) >= 48;
}

// ---- fused prep: self-sniff + exact-fp32 row norms + fp8 e4m3 operand copy.
// (R8-verified) ----
__global__ __launch_bounds__(256) void prep_all_kernel(
    const void* __restrict__ Xin, const void* __restrict__ Ein,
    unsigned char* __restrict__ Xf8, unsigned char* __restrict__ Ef8,
    float* __restrict__ x2, float* __restrict__ e2) {
  const int lane  = threadIdx.x & 63;
  const int wavei = threadIdx.x >> 6;
  const bool isbf = sniff_bf16(Xin);

  const int grow = blockIdx.x * 4 + wavei;
  const void* in; unsigned char* q; float* nrm; int row;
  if (grow < NPTS) { in = Xin; q = Xf8; nrm = x2; row = grow; }
  else             { in = Ein; q = Ef8; nrm = e2; row = grow - NPTS; }

  unsigned char* qq = q + (size_t)row * DIM;
  float s = 0.f;
#pragma unroll
  for (int it = 0; it < 4; ++it) {
    float v0, v1, v2, v3, v4, v5, v6, v7;
    if (isbf) {
      const unsigned short* p = (const unsigned short*)in + (size_t)row * DIM;
      uint4 r = *(const uint4*)(p + it * 512 + lane * 8);
      v0 = bflo(r.x); v1 = bfhi(r.x); v2 = bflo(r.y); v3 = bfhi(r.y);
      v4 = bflo(r.z); v5 = bfhi(r.z); v6 = bflo(r.w); v7 = bfhi(r.w);
    } else {
      const float* p = (const float*)in + (size_t)row * DIM;
      float4 a = *(const float4*)(p + it * 512 + lane * 8);
      float4 b = *(const float4*)(p + it * 512 + lane * 8 + 4);
      v0 = a.x; v1 = a.y; v2 = a.z; v3 = a.w;
      v4 = b.x; v5 = b.y; v6 = b.z; v7 = b.w;
    }
    s += v0 * v0 + v1 * v1 + v2 * v2 + v3 * v3;
    s += v4 * v4 + v5 * v5 + v6 * v6 + v7 * v7;
    uint2 w;
    w.x = cvtpk4(v0, v1, v2, v3);
    w.y = cvtpk4(v4, v5, v6, v7);
    *(uint2*)(qq + it * 512 + lane * 8) = w;
  }
#pragma unroll
  for (int off = 32; off > 0; off >>= 1) s += __shfl_down(s, off, 64);
  if (lane == 0) nrm[row] = s;
}

// ---- 256x256 8-wave MX-fp8 GEMM: mfma_scale_f32_16x16x128_f8f6f4 with
//      uniform scale 1.0 (E8M0 0x7F). BK=128 -> 16 K-tiles, 2-buffer LDS
//      (2 x 64KB), 2-barrier body, entry vmcnt(8), stage t+2 after exit
//      barrier. Both-sides XOR swizzle (rule #21). R8/R10-verified @ ~508 us
//      total (1440 TF eff = 88% of m148's same-structure reference).
//      Session-tested and rejected: single-buffer TLP (R9, VGPR-capped at
//      8 waves/CU -> no 2nd block possible), early-drain barrier (R11, +9us),
//      XCD remap (R4), BK=64/32x32 (R7), plain fp8 (R6). Occupancy is
//      VGPR-bound (128 acc regs inherent to 256^2/8-wave), not LDS-bound. ----
__global__ __launch_bounds__(512, 2) void gemm_mx_kernel(
    const void* __restrict__ Xin,            // output-dtype sniff only
    const unsigned char* __restrict__ X8, const unsigned char* __restrict__ E8,
    const float* __restrict__ x2, const float* __restrict__ e2,
    void* __restrict__ outv) {
  // [buf][ A: 256x128 fp8 (32KB) | B: 256x128 fp8 (32KB) ] = 2 x 64KB = 128KB
  __shared__ __align__(16) unsigned char sbuf[2][65536];

  const int tid  = threadIdx.x;
  const int lane = tid & 63;
  const int wave = tid >> 6;   // 0..7
  const int wm   = wave >> 2;  // 0..1  (M half: 128 rows)
  const int wn   = wave & 3;   // 0..3  (N quarter: 64 cols)
  const int quad = lane >> 4;
  const int l16  = lane & 15;

  const bool isbf = sniff_bf16(Xin);

  const int rowBase = blockIdx.y * 256;
  const int colBase = blockIdx.x * 256;

  // Staging: 8 gloads/thread/tile. gload g covers rows [g*64, g*64+64) (8KB).
  // Thread t: dest row = g*64 + (t>>3), dest col-byte = (t&7)*16 (linear).
  // Inverse-swizzled SOURCE col: ((t&7) ^ ((t>>3)&7)) * 16 bytes.
  const int srow  = tid >> 3;                         // 0..63
  const int scol  = ((tid & 7) ^ (srow & 7)) * 16;    // source col (bytes)
  size_t gAo[4], gBo[4];
#pragma unroll
  for (int g = 0; g < 4; ++g) {
    gAo[g] = (size_t)(rowBase + g * 64 + srow) * DIM + scol;
    gBo[g] = (size_t)(colBase + g * 64 + srow) * DIM + scol;
  }

  // Fragment reads (16x16x128): lane -> row = l16 (+16*frag), k = quad*32+[0,32)
  // = two b128 at swizzled cb = ((quad*2 + h) ^ (l16&7)) * 16, h = 0,1.
  const int cb0 = ((quad * 2) ^ (l16 & 7)) * 16;

  f32x4 acc[8][4];
#pragma unroll
  for (int mt = 0; mt < 8; ++mt)
#pragma unroll
    for (int nt = 0; nt < 4; ++nt) acc[mt][nt] = f32x4{0.f, 0.f, 0.f, 0.f};

  i32x8 a8[4], b8[4];

#define STAGE(t_) do { unsigned char* sb_ = sbuf[(t_) & 1];                     \
    const size_t kk_ = (size_t)(t_) * BKF;                                      \
    _Pragma("unroll") for (int g = 0; g < 4; ++g)                               \
      gload16(X8 + gAo[g] + kk_, sb_ + g * 8192 + wave * 1024);                 \
    _Pragma("unroll") for (int g = 0; g < 4; ++g)                               \
      gload16(E8 + gBo[g] + kk_, sb_ + 32768 + g * 8192 + wave * 1024);         \
  } while (0)

  // Load one i32x8 fragment (32 fp8 = k quad*32..+32) from swizzled LDS row.
#define LDFRAG(dst_, base_, rowi_) do {                                         \
    const unsigned char* p_ = (base_) + (rowi_) * 128;                          \
    i32x4 lo_ = *(const i32x4*)(const void*)(p_ + cb0);                         \
    i32x4 hi_ = *(const i32x4*)(const void*)(p_ + (cb0 ^ 16));                  \
    dst_[0] = lo_[0]; dst_[1] = lo_[1]; dst_[2] = lo_[2]; dst_[3] = lo_[3];     \
    dst_[4] = hi_[0]; dst_[5] = hi_[1]; dst_[6] = hi_[2]; dst_[7] = hi_[3];     \
  } while (0)

#define MFMA16(MOFF_) do {                                                      \
    __builtin_amdgcn_s_setprio(1);                                              \
    _Pragma("unroll") for (int m = 0; m < 4; ++m)                               \
      _Pragma("unroll") for (int n = 0; n < 4; ++n)                             \
        acc[(MOFF_) + m][n] = __builtin_amdgcn_mfma_scale_f32_16x16x128_f8f6f4( \
            a8[m], b8[n], acc[(MOFF_) + m][n], 0, 0,                            \
            0, 0x7F7F7F7F, 0, 0x7F7F7F7F);   /* E8M0 0x7F = scale 1.0 */        \
    __builtin_amdgcn_s_setprio(0);                                              \
  } while (0)

  // Race audit (R8): entry {vmcnt(8); barrier} -> tile t's 8 loads (oldest
  // outstanding) landed for every wave before its barrier arrival -> tile t
  // fully resident after barrier. All ds_reads of buf[t&1] complete before
  // each wave's MFMAs issue (compiler lgkm waits), hence before the exit
  // barrier; STAGE(t+2) overwriting buf[t&1] is issued only after it.
#define BODY(t_, DOSTAGE_, VMS_) do {                                           \
    asm volatile("s_waitcnt vmcnt(" VMS_ ")" ::: "memory");                     \
    __builtin_amdgcn_s_barrier();                                               \
    __builtin_amdgcn_sched_barrier(0);                                          \
    const unsigned char* sa_ = sbuf[(t_) & 1];                                  \
    const unsigned char* sb2_ = sa_ + 32768;                                    \
    _Pragma("unroll") for (int m = 0; m < 4; ++m)                               \
      LDFRAG(a8[m], sa_, (wm * 128 + m * 16 + l16));                            \
    _Pragma("unroll") for (int n = 0; n < 4; ++n)                               \
      LDFRAG(b8[n], sb2_, (wn * 64 + n * 16 + l16));                            \
    MFMA16(0);                                                                  \
    _Pragma("unroll") for (int m = 0; m < 4; ++m)                               \
      LDFRAG(a8[m], sa_, (wm * 128 + (m + 4) * 16 + l16));                      \
    MFMA16(4);                                                                  \
    asm volatile("" ::: "memory");                                              \
    __builtin_amdgcn_s_barrier();                                               \
    __builtin_amdgcn_sched_barrier(0);                                          \
    if (DOSTAGE_) STAGE((t_) + 2);                                              \
  } while (0)

  // Prologue: tiles 0,1 staged (16 loads/thread).
  STAGE(0); STAGE(1);

#pragma unroll 1
  for (int t = 0; t < NTF - 2; ++t) {
    BODY(t, true, "8");
  }
  BODY(NTF - 2, false, "8");
  BODY(NTF - 1, false, "0");
#undef BODY
#undef MFMA16
#undef LDFRAG
#undef STAGE

  // Epilogue. 16x16 C/D layout: col = lane&15, row = quad*4 + reg
  // (shape-determined, FMT-independent — R8-verified).
  float ec[4];
#pragma unroll
  for (int nt = 0; nt < 4; ++nt) ec[nt] = e2[colBase + wn * 64 + nt * 16 + l16];

  if (isbf) {
    unsigned short* out = (unsigned short*)outv;
#pragma unroll
    for (int mt = 0; mt < 8; ++mt)
#pragma unroll
      for (int r2 = 0; r2 < 4; ++r2) {
        const int row = rowBase + wm * 128 + mt * 16 + quad * 4 + r2;
        const float xr = x2[row];
#pragma unroll
        for (int nt = 0; nt < 4; ++nt) {
          const int col = colBase + wn * 64 + nt * 16 + l16;
          float sq = xr + ec[nt] - 2.0f * acc[mt][nt][r2];
          sq = sq > 0.f ? sq : 0.f;
          out[(size_t)row * NGRP + col] = f2bf(-__builtin_sqrtf(sq));
        }
      }
  } else {
    float* out = (float*)outv;
#pragma unroll
    for (int mt = 0; mt < 8; ++mt)
#pragma unroll
      for (int r2 = 0; r2 < 4; ++r2) {
        const int row = rowBase + wm * 128 + mt * 16 + quad * 4 + r2;
        const float xr = x2[row];
#pragma unroll
        for (int nt = 0; nt < 4; ++nt) {
          const int col = colBase + wn * 64 + nt * 16 + l16;
          float sq = xr + ec[nt] - 2.0f * acc[mt][nt][r2];
          sq = sq > 0.f ? sq : 0.f;
          out[(size_t)row * NGRP + col] = -__builtin_sqrtf(sq);
        }
      }
  }
}

// ---------------- fallback path (workspace too small): round-0 kernels ----------------

__global__ void sniff_kernel(const unsigned short* __restrict__ X, int* __restrict__ flag) {
  if (threadIdx.x == 0 && blockIdx.x == 0) {
    int c = 0;
    for (int i = 0; i < 64; ++i) {
      unsigned b = (X[i] >> 8) & 0x7F;
      c += (b >= 0x3B && b <= 0x41) ? 1 : 0;
    }
    *flag = (c >= 48) ? 1 : 0;
  }
}

__global__ __launch_bounds__(256) void rownorm_kernel(const void* __restrict__ in,
                                                      float* __restrict__ out,
                                                      const int* __restrict__ flag) {
  const int wave = threadIdx.x >> 6;
  const int lane = threadIdx.x & 63;
  const int row  = blockIdx.x * 4 + wave;
  float s = 0.f;
  if (*flag) {
    const unsigned short* p = (const unsigned short*)in + (size_t)row * DIM;
#pragma unroll
    for (int it = 0; it < 4; ++it) {
      uint4 v = *(const uint4*)(p + it * 512 + lane * 8);
      float f;
      f = bflo(v.x); s += f * f;  f = bfhi(v.x); s += f * f;
      f = bflo(v.y); s += f * f;  f = bfhi(v.y); s += f * f;
      f = bflo(v.z); s += f * f;  f = bfhi(v.z); s += f * f;
      f = bflo(v.w); s += f * f;  f = bfhi(v.w); s += f * f;
    }
  } else {
    const float* p = (const float*)in + (size_t)row * DIM;
#pragma unroll
    for (int it = 0; it < 4; ++it) {
      float4 a = *(const float4*)(p + it * 512 + lane * 8);
      float4 b = *(const float4*)(p + it * 512 + lane * 8 + 4);
      s += a.x * a.x + a.y * a.y + a.z * a.z + a.w * a.w;
      s += b.x * b.x + b.y * b.y + b.z * b.z + b.w * b.w;
    }
  }
#pragma unroll
  for (int off = 32; off > 0; off >>= 1) s += __shfl_down(s, off, 64);
  if (lane == 0) out[row] = s;
}

__device__ __forceinline__ u16x8 cvt8(const float* p) {
  float4 a = *(const float4*)p;
  float4 b = *(const float4*)(p + 4);
  u16x8 r;
  r[0] = f2bf(a.x); r[1] = f2bf(a.y); r[2] = f2bf(a.z); r[3] = f2bf(a.w);
  r[4] = f2bf(b.x); r[5] = f2bf(b.y); r[6] = f2bf(b.z); r[7] = f2bf(b.w);
  return r;
}

__global__ __launch_bounds__(256) void gemm_dist_kernel(
    const void* __restrict__ Xv, const void* __restrict__ Ev,
    const float* __restrict__ x2, const float* __restrict__ e2,
    void* __restrict__ outv, const int* __restrict__ flag) {
  __shared__ __align__(16) unsigned short sA[128 * 32];
  __shared__ __align__(16) unsigned short sB[128 * 32];

  const bool isbf = (*flag != 0);
  const int tid  = threadIdx.x;
  const int lane = tid & 63;
  const int wave = tid >> 6;
  const int wm   = wave >> 1;
  const int wn   = wave & 1;
  const int quad = lane >> 4;
  const int l16  = lane & 15;

  const int rowBase = blockIdx.y * 128;
  const int colBase = blockIdx.x * 128;

  const int flat0 = tid * 8;
  const int flat1 = (tid + 256) * 8;
  const int r0 = flat0 >> 5, c0 = flat0 & 31;
  const int r1 = flat1 >> 5, c1 = flat1 & 31;

  const size_t iA0 = (size_t)(rowBase + r0) * DIM + c0;
  const size_t iA1 = (size_t)(rowBase + r1) * DIM + c1;
  const size_t iB0 = (size_t)(colBase + r0) * DIM + c0;
  const size_t iB1 = (size_t)(colBase + r1) * DIM + c1;

  f32x4 zero = {0.f, 0.f, 0.f, 0.f};
  f32x4 acc[4][4];
#pragma unroll
  for (int mt = 0; mt < 4; ++mt)
#pragma unroll
    for (int nt = 0; nt < 4; ++nt) acc[mt][nt] = zero;

  for (int k0 = 0; k0 < DIM; k0 += 32) {
    if (isbf) {
      const unsigned short* X = (const unsigned short*)Xv;
      const unsigned short* E = (const unsigned short*)Ev;
      *(uint4*)(sA + flat0) = *(const uint4*)(X + iA0 + k0);
      *(uint4*)(sA + flat1) = *(const uint4*)(X + iA1 + k0);
      *(uint4*)(sB + flat0) = *(const uint4*)(E + iB0 + k0);
      *(uint4*)(sB + flat1) = *(const uint4*)(E + iB1 + k0);
    } else {
      const float* X = (const float*)Xv;
      const float* E = (const float*)Ev;
      *(u16x8*)(sA + flat0) = cvt8(X + iA0 + k0);
      *(u16x8*)(sA + flat1) = cvt8(X + iA1 + k0);
      *(u16x8*)(sB + flat0) = cvt8(E + iB0 + k0);
      *(u16x8*)(sB + flat1) = cvt8(E + iB1 + k0);
    }
    __syncthreads();

    bf16x8 a[4], b[4];
#pragma unroll
    for (int mt = 0; mt < 4; ++mt)
      a[mt] = *(const bf16x8*)(const void*)(sA + (wm * 64 + mt * 16 + l16) * 32 + quad * 8);
#pragma unroll
    for (int nt = 0; nt < 4; ++nt)
      b[nt] = *(const bf16x8*)(const void*)(sB + (wn * 64 + nt * 16 + l16) * 32 + quad * 8);
#pragma unroll
    for (int mt = 0; mt < 4; ++mt)
#pragma unroll
      for (int nt = 0; nt < 4; ++nt)
        acc[mt][nt] = __builtin_amdgcn_mfma_f32_16x16x32_bf16(a[mt], b[nt], acc[mt][nt], 0, 0, 0);
    __syncthreads();
  }

  float ec[4];
#pragma unroll
  for (int nt = 0; nt < 4; ++nt) ec[nt] = e2[colBase + wn * 64 + nt * 16 + l16];

  if (isbf) {
    unsigned short* out = (unsigned short*)outv;
#pragma unroll
    for (int mt = 0; mt < 4; ++mt)
#pragma unroll
      for (int r = 0; r < 4; ++r) {
        const int row = rowBase + wm * 64 + mt * 16 + quad * 4 + r;
        const float xr = x2[row];
#pragma unroll
        for (int nt = 0; nt < 4; ++nt) {
          const int col = colBase + wn * 64 + nt * 16 + l16;
          float sq = xr + ec[nt] - 2.0f * acc[mt][nt][r];
          sq = sq > 0.f ? sq : 0.f;
          out[(size_t)row * NGRP + col] = f2bf(-__builtin_sqrtf(sq));
        }
      }
  } else {
    float* out = (float*)outv;
#pragma unroll
    for (int mt = 0; mt < 4; ++mt)
#pragma unroll
      for (int r = 0; r < 4; ++r) {
        const int row = rowBase + wm * 64 + mt * 16 + quad * 4 + r;
        const float xr = x2[row];
#pragma unroll
        for (int nt = 0; nt < 4; ++nt) {
          const int col = colBase + wn * 64 + nt * 16 + l16;
          float sq = xr + ec[nt] - 2.0f * acc[mt][nt][r];
          sq = sq > 0.f ? sq : 0.f;
          out[(size_t)row * NGRP + col] = -__builtin_sqrtf(sq);
        }
      }
  }
}

extern "C" void kernel_launch(void* const* d_in, const int* in_sizes, int n_in,
                              void* d_out, int out_size, void* d_ws, size_t ws_size,
                              hipStream_t stream) {
  const size_t xf8 = (size_t)NPTS * DIM;
  const size_t ef8 = (size_t)NGRP * DIM;
  const size_t need = xf8 + ef8 + (NPTS + NGRP) * sizeof(float) + 64;

  if (ws_size >= need) {
    // Fast path: fused prep (exact norms + fp8 copy) + MX-fp8 K=128 GEMM
    // (R8-verified double-buffer structure — session best, ~508 us).
    unsigned char* Xf8 = (unsigned char*)d_ws;
    unsigned char* Ef8 = Xf8 + xf8;
    float* x2 = (float*)(Ef8 + ef8);
    float* e2 = x2 + NPTS;

    prep_all_kernel<<<(NPTS + NGRP) / 4, 256, 0, stream>>>(d_in[0], d_in[1],
                                                           Xf8, Ef8, x2, e2);
    dim3 grid(NGRP / 256, NPTS / 256);
    gemm_mx_kernel<<<grid, 512, 0, stream>>>(d_in[0], Xf8, Ef8, x2, e2, d_out);
  } else {
    // Fallback: round-0 verified bf16 path.
    float* x2 = (float*)d_ws;
    float* e2 = x2 + NPTS;
    int* flag = (int*)(e2 + NGRP);

    sniff_kernel<<<1, 64, 0, stream>>>((const unsigned short*)d_in[0], flag);
    rownorm_kernel<<<NPTS / 4, 256, 0, stream>>>(d_in[0], x2, flag);
    rownorm_kernel<<<NGRP / 4, 256, 0, stream>>>(d_in[1], e2, flag);
    dim3 grid(NGRP / 128, NPTS / 128);
    gemm_dist_kernel<<<grid, 256, 0, stream>>>(d_in[0], d_in[1], x2, e2, d_out, flag);
  }
}